// Round 5
// baseline (3588.565 us; speedup 1.0000x reference)
//
#include <hip/hip_runtime.h>
#include <hip/hip_bf16.h>
#include <stdint.h>

// ---------------------------------------------------------------------------
// 2-layer LSTM (B=256, T=1024, H=256), persistent clusters, self-paced
// dataflow. R13: TAG-IN-LINE data publish.
//
// R8..R12 evidence: period is set by the exchange protocol's serialized
// coherent RTs (R9 calibration: +1 poll RT = +0.49us/step). R13 changes the
// protocol, not the work around it:
//  - h is published as 8B atomic chunks {2 bf16, 4B step-tag} (dwordx2).
//    Consumers poll the DATA: one batched read = detect + fetch (1 RT).
//    Tag==t implies that chunk's payload is fresh (8B single-copy atomic),
//    so there is no flag/data read-order race.
//  - No producer release drain: stores are fire-and-forget; the NEXT step's
//    poll vmcnt(0) is the release point backing the progress flags.
//  - Flags only carry "staged" progress for overwrite guards (>=2-step
//    slack, always fast-path): value v == "poll of step v-1 passed" ==
//    "fetched h(.) of step v-1, stores of step v-2 acked". All guards are
//    the uniform check flag >= t-1.
//  - op: 8 slots; reducer handles column t-4; op loads issue right after
//    barrier#1 and bind just before the h-store -> the rotating reduce
//    straggler (~1.3k cy/step, identified R12) collapses to ~100 cy.
//  - 2 barriers/step (LDS tile WAR). All polls have iteration bailouts so a
//    protocol bug fails visibly instead of hanging.
// ---------------------------------------------------------------------------

#define TT 1024
#define NC 16

typedef __attribute__((ext_vector_type(8))) short  bfrag;
typedef __attribute__((ext_vector_type(4))) float  ffrag;
typedef __attribute__((ext_vector_type(4))) int    ifrag;

__device__ __forceinline__ float sigf(float v){ return 1.f/(1.f+__expf(-v)); }
__device__ __forceinline__ float tanhfast(float v){
    v = fminf(fmaxf(v,-15.f),15.f);
    float e = __expf(2.f*v);
    return (e-1.f)/(e+1.f);
}
__device__ __forceinline__ void st32(uint32_t* p, uint32_t v){
    __hip_atomic_store(p, v, __ATOMIC_RELAXED, __HIP_MEMORY_SCOPE_AGENT);
}
__device__ __forceinline__ void st64(unsigned long long* p, unsigned long long v){
    __hip_atomic_store(p, v, __ATOMIC_RELAXED, __HIP_MEMORY_SCOPE_AGENT);
}
__device__ __forceinline__ void stf(float* p, float v){
    __hip_atomic_store(p, v, __ATOMIC_RELAXED, __HIP_MEMORY_SCOPE_AGENT);
}
__device__ __forceinline__ void drain_vmem(){
    __asm__ volatile("s_waitcnt vmcnt(0)" ::: "memory");
}
__device__ __forceinline__ float2 ldf2_coh(const float* p1, const float* p2){
    float a, b;
    __asm__ volatile(
        "global_load_dword %0, %2, off sc0 sc1\n\t"
        "global_load_dword %1, %3, off sc0 sc1\n\t"
        "s_waitcnt vmcnt(0)"
        : "=&v"(a), "=&v"(b) : "v"(p1), "v"(p2) : "memory");
    return make_float2(a, b);
}
// 4x4 transpose across (reg index) x (lane bits 0-1) - R11/R12-proven.
__device__ __forceinline__ void xpose4(ffrag& a, int lane){
    float x0 = (lane&1) ? a[0] : a[1];
    float y0 = __shfl_xor(x0, 1);
    a[0] = (lane&1) ? y0 : a[0];  a[1] = (lane&1) ? a[1] : y0;
    float x1 = (lane&1) ? a[2] : a[3];
    float y1 = __shfl_xor(x1, 1);
    a[2] = (lane&1) ? y1 : a[2];  a[3] = (lane&1) ? a[3] : y1;
    float x2 = (lane&2) ? a[0] : a[2];
    float y2 = __shfl_xor(x2, 2);
    a[0] = (lane&2) ? y2 : a[0];  a[2] = (lane&2) ? a[2] : y2;
    float x3 = (lane&2) ? a[1] : a[3];
    float y3 = __shfl_xor(x3, 2);
    a[1] = (lane&2) ? y3 : a[1];  a[3] = (lane&2) ? a[3] : y3;
}

__global__ void __launch_bounds__(256, 1)
lstm_kernel(const float* __restrict__ x,
            const float* __restrict__ Wih0, const float* __restrict__ Whh0,
            const float* __restrict__ bih0, const float* __restrict__ bhh0,
            const float* __restrict__ Wih1, const float* __restrict__ Whh1,
            const float* __restrict__ bih1, const float* __restrict__ bhh1,
            const float* __restrict__ Wlin, const float* __restrict__ blin,
            float* __restrict__ out, char* __restrict__ ws)
{
    const int tid = threadIdx.x;
    const int wg  = blockIdx.x;
    const int c   = wg >> 4;
    const int j   = wg & 15;
    const bool isL0 = (j < 8);
    const int  u0   = (isL0 ? j : (j - 8)) * 32;

    // ws: flags 16c x 16WG x 128B = 64KB
    //     h0 tagged: [4 slots][NC][8 prod][16 rows][16 chunks x 8B] = 1MB
    //     h1 tagged: 1MB
    //     op: [8 slots][NC][32 partials][16 rows] fp32 = 256KB
    int* flagbase = (int*)(ws + c * 4096);
    uint32_t* h0w = (uint32_t*)(ws + 65536);
    uint32_t* h1w = h0w + 4 * NC * 8 * 512;
    float*    op  = (float*)(h1w + 4 * NC * 8 * 512);

    // LDS: Wt 64KB | Wt2/xs 64KB (aliased) | hs0 8KB | hs1 8KB
    __shared__ __attribute__((aligned(16))) char S[147456];
    __hip_bfloat16* Wt  = (__hip_bfloat16*)S;            // L0: Whh0; L1: Wih1
    __hip_bfloat16* Wt2 = (__hip_bfloat16*)(S + 65536);  // L1: Whh1
    float*          xs  = (float*)(S + 65536);           // L0: x fp32 [t][16]
    char*           hs0 = (char*)(S + 131072);
    char*           hs1 = (char*)(S + 139264);

    const int lane = tid & 63, wave = tid >> 6;
    const int q_l  = (lane >> 2) & 3;
    const int g_l  = lane & 3;
    const int rg   = lane >> 4;
    const int row  = rg * 4 + g_l;          // batch row within cluster (0..15)
    const int u_e  = wave * 8 + q_l * 2;    // local unit (even), u_o = u_e+1

    // ---- one-time init (R11/R12-proven W permutation pack) ----
    {
        const float* Wsrc = isL0 ? Whh0 : Wih1;
        for (int i = tid; i < 128 * 256; i += 256) {
            int n = i >> 8, k = i & 255;
            int ntile = n >> 4, cc = n & 15, q = cc >> 2, g = cc & 3;
            int unit = 8 * (ntile >> 1) + 2 * q + (ntile & 1);
            int r = g * 256 + u0 + unit;
            int ln = (n & 15) | (((k >> 3) & 3) << 4);
            int toff = (ntile * 8 + (k >> 5)) * 1024 + ln * 16 + (k & 7) * 2;
            *(__hip_bfloat16*)((char*)Wt + toff) = __float2bfloat16(Wsrc[r * 256 + k]);
            if (!isL0)
                *(__hip_bfloat16*)((char*)Wt2 + toff) = __float2bfloat16(Whh1[r * 256 + k]);
        }
        if (isL0) {
            for (int i = tid; i < 16 * 1024; i += 256)   // xs[t][16 rows]
                xs[i] = x[(c * 16 + (i & 15)) * TT + (i >> 4)];
        }
        // zero own h(-1) slot-3 block (data 0, tag 0) - 2KB = 256 x 8B
        unsigned long long* z = (unsigned long long*)
            (isL0 ? (h0w + ((3 * NC + c) * 8 + j) * 512)
                  : (h1w + ((3 * NC + c) * 8 + (j - 8)) * 512));
        st64(z + tid, 0ull);
    }
    // per-lane constants (regs)
    float be0,be1,be2,be3, bo0,bo1,bo2,bo3;
    float we0=0,we1=0,we2=0,we3=0, wo0=0,wo1=0,wo2=0,wo3=0;
    float wle=0, wlo=0;
    {
        const float* bi = isL0 ? bih0 : bih1;
        const float* bh = isL0 ? bhh0 : bhh1;
        int r0 = u0 + u_e;
        be0 = bi[r0] + bh[r0];               bo0 = bi[r0+1] + bh[r0+1];
        be1 = bi[256+r0] + bh[256+r0];       bo1 = bi[256+r0+1] + bh[256+r0+1];
        be2 = bi[512+r0] + bh[512+r0];       bo2 = bi[512+r0+1] + bh[512+r0+1];
        be3 = bi[768+r0] + bh[768+r0];       bo3 = bi[768+r0+1] + bh[768+r0+1];
        if (isL0) {
            we0 = Wih0[r0];     wo0 = Wih0[r0+1];
            we1 = Wih0[256+r0]; wo1 = Wih0[256+r0+1];
            we2 = Wih0[512+r0]; wo2 = Wih0[512+r0+1];
            we3 = Wih0[768+r0]; wo3 = Wih0[768+r0+1];
        } else {
            wle = Wlin[u0 + u_e]; wlo = Wlin[u0 + u_e + 1];
        }
    }
    const float blin_r = blin[0];
    drain_vmem();
    __syncthreads();
    if (tid == 0) st32((uint32_t*)(flagbase + j * 32), 0u);  // redundant w/ memset

    // flag lines (R8 geometry): my 4 dep flags on private 128B lines
    const int* fL0a = flagbase + (wave)      * 32;
    const int* fL0b = flagbase + (wave + 4)  * 32;
    const int* fL1a = flagbase + (8 + wave)  * 32;
    const int* fL1b = flagbase + (12 + wave) * 32;
    int* myflag = (int*)(flagbase + j * 32);

    // Wt bases for this wave's 2 n-tiles
    const char* wb0 = (const char*)Wt + (wave * 2) * 8192 + lane * 16;
    const char* wb1 = wb0 + 8192;
    const char* wc0 = (const char*)Wt2 + (wave * 2) * 8192 + lane * 16;
    const char* wc1 = wc0 + 8192;
    // per-lane fragment offset within a tagged 2KB block:
    // row=(lane&15) stride 128B, fr=(lane>>4) -> chunks 4fr..4fr+3 (32B)
    const int lnoff = (lane & 15) * 128 + (lane >> 4) * 32;

    float c0a = 0.f, c0b = 0.f;

    if (isL0) {
        for (int t = 0; t < TT; ++t) {
            // ---- poll = detect + fetch: h0(t-1) tags == t; flags >= t-1 ----
            const char* tb = (const char*)h0w + ((((t + 3) & 3) * NC + c) * 8) * 2048 + lnoff;
            const char* p0 = tb + wave * 2048;
            const char* p1 = p0 + 8192;
            ifrag r0, r1, r2, r3; int f0, f1, f2, f3;
            const int tagv = t, tgt = t - 1;
            int bail = 0;
            for (;;) {
                __asm__ volatile(
                    "global_load_dwordx4 %0, %8, off sc0 sc1\n\t"
                    "global_load_dwordx4 %1, %8, off offset:16 sc0 sc1\n\t"
                    "global_load_dwordx4 %2, %9, off sc0 sc1\n\t"
                    "global_load_dwordx4 %3, %9, off offset:16 sc0 sc1\n\t"
                    "global_load_dword %4, %10, off sc0 sc1\n\t"
                    "global_load_dword %5, %11, off sc0 sc1\n\t"
                    "global_load_dword %6, %12, off sc0 sc1\n\t"
                    "global_load_dword %7, %13, off sc0 sc1\n\t"
                    "s_waitcnt vmcnt(0)"
                    : "=&v"(r0), "=&v"(r1), "=&v"(r2), "=&v"(r3),
                      "=&v"(f0), "=&v"(f1), "=&v"(f2), "=&v"(f3)
                    : "v"(p0), "v"(p1), "v"(fL0a), "v"(fL0b), "v"(fL1a), "v"(fL1b)
                    : "memory");
                bool ok = (r0.y==tagv) & (r0.w==tagv) & (r1.y==tagv) & (r1.w==tagv)
                        & (r2.y==tagv) & (r2.w==tagv) & (r3.y==tagv) & (r3.w==tagv)
                        & (f0>=tgt) & (f1>=tgt) & (f2>=tgt) & (f3>=tgt);
                if (__all(ok)) break;
                if (++bail > (1<<21)) break;      // fail visibly, never hang
                __builtin_amdgcn_s_sleep(1);
            }
            // fragments -> LDS (strip tags: data dwords are .x/.z)
            *(ifrag*)(hs0 + wave * 1024 + lane * 16)       = (ifrag){r0.x, r0.z, r1.x, r1.z};
            *(ifrag*)(hs0 + (wave + 4) * 1024 + lane * 16) = (ifrag){r2.x, r2.z, r3.x, r3.z};
            __syncthreads();                      // barrier #1: tiles ready
            if (tid == 0) st32((uint32_t*)myflag, (uint32_t)(t + 1));  // staged t

            const bool red = (t >= 4) && (j == ((t - 4) & 7));
            float ra = 0.f, rb = 0.f;
            if (red) {                            // op col t-4: issue early
                int slot = (t - 4) & 7;
                const float* o1 = op + ((slot * NC + c) * 32 + (tid & 15)) * 16 + (tid >> 4);
                const float* o2 = o1 + 256;
                __asm__ volatile(
                    "global_load_dword %0, %2, off sc0 sc1\n\t"
                    "global_load_dword %1, %3, off sc0 sc1"
                    : "=&v"(ra), "=&v"(rb) : "v"(o1), "v"(o2) : "memory");
            }

            ffrag a0 = {0.f,0.f,0.f,0.f}, a1 = {0.f,0.f,0.f,0.f};
            #pragma unroll
            for (int kt = 0; kt < 8; ++kt) {
                bfrag av = *(const bfrag*)(hs0 + kt * 1024 + lane * 16);
                bfrag b0 = *(const bfrag*)(wb0 + kt * 1024);
                bfrag b1 = *(const bfrag*)(wb1 + kt * 1024);
                a0 = __builtin_amdgcn_mfma_f32_16x16x32_bf16(av, b0, a0, 0, 0, 0);
                a1 = __builtin_amdgcn_mfma_f32_16x16x32_bf16(av, b1, a1, 0, 0, 0);
            }
            __syncthreads();                      // barrier #2: LDS reads done
            xpose4(a0, lane);
            xpose4(a1, lane);

            float xv = xs[t * 16 + row];
            float iv = a0[0] + fmaf(xv, we0, be0);
            float fv = a0[1] + fmaf(xv, we1, be1);
            float gv = a0[2] + fmaf(xv, we2, be2);
            float ov = a0[3] + fmaf(xv, we3, be3);
            c0a = sigf(fv) * c0a + sigf(iv) * tanhfast(gv);
            float hn0 = sigf(ov) * tanhfast(c0a);
            iv = a1[0] + fmaf(xv, wo0, bo0);
            fv = a1[1] + fmaf(xv, wo1, bo1);
            gv = a1[2] + fmaf(xv, wo2, bo2);
            ov = a1[3] + fmaf(xv, wo3, bo3);
            c0b = sigf(fv) * c0b + sigf(iv) * tanhfast(gv);
            float hn1 = sigf(ov) * tanhfast(c0b);

            __hip_bfloat16 hb0 = __float2bfloat16(hn0), hb1 = __float2bfloat16(hn1);
            uint32_t pk = ((uint32_t)(*(uint16_t*)&hb1) << 16) | (uint32_t)(*(uint16_t*)&hb0);

            if (red) {                            // bind op before h-store
                __asm__ volatile("s_waitcnt vmcnt(0)" : "+v"(ra), "+v"(rb) :: "memory");
            }
            // publish h0(t): one 8B atomic chunk per thread {data, tag t+1}
            st64((unsigned long long*)
                 (h0w + (((t & 3) * NC + c) * 8 + j) * 512 + row * 32 + (wave * 4 + q_l) * 2),
                 (unsigned long long)pk | ((unsigned long long)(uint32_t)(t + 1) << 32));
            if (red) {                            // ~100cy shuffles, off-chain
                float v = ra + rb;
                v += __shfl_down(v, 8, 16);
                v += __shfl_down(v, 4, 16);
                v += __shfl_down(v, 2, 16);
                v += __shfl_down(v, 1, 16);
                if ((tid & 15) == 0) out[(c * 16 + (tid >> 4)) * TT + (t - 4)] = v + blin_r;
            }
        }
    } else {
        for (int t = 0; t < TT; ++t) {
            // ---- poll: h0(t) tags == t+1; h1(t-1) tags == t; flags >= t-1 ----
            const char* tb0 = (const char*)h0w + (((t & 3) * NC + c) * 8) * 2048 + lnoff;
            const char* p0 = tb0 + wave * 2048;
            const char* p1 = p0 + 8192;
            const char* tb1 = (const char*)h1w + ((((t + 3) & 3) * NC + c) * 8) * 2048 + lnoff;
            const char* p2 = tb1 + wave * 2048;
            const char* p3 = p2 + 8192;
            ifrag r0, r1, r2, r3, r4, r5, r6, r7; int f0, f1, f2, f3;
            const int tag0 = t + 1, tag1 = t, tgt = t - 1;
            int bail = 0;
            for (;;) {
                __asm__ volatile(
                    "global_load_dwordx4 %0, %12, off sc0 sc1\n\t"
                    "global_load_dwordx4 %1, %12, off offset:16 sc0 sc1\n\t"
                    "global_load_dwordx4 %2, %13, off sc0 sc1\n\t"
                    "global_load_dwordx4 %3, %13, off offset:16 sc0 sc1\n\t"
                    "global_load_dwordx4 %4, %14, off sc0 sc1\n\t"
                    "global_load_dwordx4 %5, %14, off offset:16 sc0 sc1\n\t"
                    "global_load_dwordx4 %6, %15, off sc0 sc1\n\t"
                    "global_load_dwordx4 %7, %15, off offset:16 sc0 sc1\n\t"
                    "global_load_dword %8, %16, off sc0 sc1\n\t"
                    "global_load_dword %9, %17, off sc0 sc1\n\t"
                    "global_load_dword %10, %18, off sc0 sc1\n\t"
                    "global_load_dword %11, %19, off sc0 sc1\n\t"
                    "s_waitcnt vmcnt(0)"
                    : "=&v"(r0), "=&v"(r1), "=&v"(r2), "=&v"(r3),
                      "=&v"(r4), "=&v"(r5), "=&v"(r6), "=&v"(r7),
                      "=&v"(f0), "=&v"(f1), "=&v"(f2), "=&v"(f3)
                    : "v"(p0), "v"(p1), "v"(p2), "v"(p3),
                      "v"(fL0a), "v"(fL0b), "v"(fL1a), "v"(fL1b)
                    : "memory");
                bool ok = (r0.y==tag0) & (r0.w==tag0) & (r1.y==tag0) & (r1.w==tag0)
                        & (r2.y==tag0) & (r2.w==tag0) & (r3.y==tag0) & (r3.w==tag0)
                        & (r4.y==tag1) & (r4.w==tag1) & (r5.y==tag1) & (r5.w==tag1)
                        & (r6.y==tag1) & (r6.w==tag1) & (r7.y==tag1) & (r7.w==tag1)
                        & (f0>=tgt) & (f1>=tgt) & (f2>=tgt) & (f3>=tgt);
                if (__all(ok)) break;
                if (++bail > (1<<21)) break;
                __builtin_amdgcn_s_sleep(1);
            }
            *(ifrag*)(hs0 + wave * 1024 + lane * 16)       = (ifrag){r0.x, r0.z, r1.x, r1.z};
            *(ifrag*)(hs0 + (wave + 4) * 1024 + lane * 16) = (ifrag){r2.x, r2.z, r3.x, r3.z};
            *(ifrag*)(hs1 + wave * 1024 + lane * 16)       = (ifrag){r4.x, r4.z, r5.x, r5.z};
            *(ifrag*)(hs1 + (wave + 4) * 1024 + lane * 16) = (ifrag){r6.x, r6.z, r7.x, r7.z};
            __syncthreads();                      // barrier #1
            if (tid == 0) st32((uint32_t*)myflag, (uint32_t)(t + 1));

            ffrag a0 = {0.f,0.f,0.f,0.f}, a1 = {0.f,0.f,0.f,0.f};
            #pragma unroll
            for (int kt = 0; kt < 8; ++kt) {       // h0(t) @ Wih1
                bfrag av = *(const bfrag*)(hs0 + kt * 1024 + lane * 16);
                bfrag b0 = *(const bfrag*)(wb0 + kt * 1024);
                bfrag b1 = *(const bfrag*)(wb1 + kt * 1024);
                a0 = __builtin_amdgcn_mfma_f32_16x16x32_bf16(av, b0, a0, 0, 0, 0);
                a1 = __builtin_amdgcn_mfma_f32_16x16x32_bf16(av, b1, a1, 0, 0, 0);
            }
            #pragma unroll
            for (int kt = 0; kt < 8; ++kt) {       // += h1(t-1) @ Whh1
                bfrag av = *(const bfrag*)(hs1 + kt * 1024 + lane * 16);
                bfrag b0 = *(const bfrag*)(wc0 + kt * 1024);
                bfrag b1 = *(const bfrag*)(wc1 + kt * 1024);
                a0 = __builtin_amdgcn_mfma_f32_16x16x32_bf16(av, b0, a0, 0, 0, 0);
                a1 = __builtin_amdgcn_mfma_f32_16x16x32_bf16(av, b1, a1, 0, 0, 0);
            }
            __syncthreads();                      // barrier #2
            xpose4(a0, lane);
            xpose4(a1, lane);

            float iv = a0[0] + be0, fv = a0[1] + be1;
            float gv = a0[2] + be2, ov = a0[3] + be3;
            c0a = sigf(fv) * c0a + sigf(iv) * tanhfast(gv);
            float hn0 = sigf(ov) * tanhfast(c0a);
            iv = a1[0] + bo0; fv = a1[1] + bo1;
            gv = a1[2] + bo2; ov = a1[3] + bo3;
            c0b = sigf(fv) * c0b + sigf(iv) * tanhfast(gv);
            float hn1 = sigf(ov) * tanhfast(c0b);

            __hip_bfloat16 hb0 = __float2bfloat16(hn0), hb1 = __float2bfloat16(hn1);
            uint32_t pk = ((uint32_t)(*(uint16_t*)&hb1) << 16) | (uint32_t)(*(uint16_t*)&hb0);

            // out partial for column t (8 op slots)
            float pv = hn0 * wle + hn1 * wlo;
            pv += __shfl_xor(pv, 4);
            pv += __shfl_xor(pv, 8);

            st64((unsigned long long*)
                 (h1w + (((t & 3) * NC + c) * 8 + (j - 8)) * 512 + row * 32 + (wave * 4 + q_l) * 2),
                 (unsigned long long)pk | ((unsigned long long)(uint32_t)(t + 1) << 32));
            if ((lane & 12) == 0)
                stf(op + (((t & 7) * NC + c) * 32 + (j - 8) * 4 + wave) * 16 + row, pv);
        }
        // final publish: drain (op cols ... acked) then staged value TT+1
        drain_vmem();
        if (tid == 0) st32((uint32_t*)myflag, (uint32_t)(TT + 1));
    }

    // tail: columns TT-4..TT-1 by L0 WGs 4..7 (need all L1 staged value TT+1)
    if (isL0 && j >= 4) {
        int f2v, f3v, bail = 0;
        for (;;) {
            __asm__ volatile(
                "global_load_dword %0, %2, off sc0 sc1\n\t"
                "global_load_dword %1, %3, off sc0 sc1\n\t"
                "s_waitcnt vmcnt(0)"
                : "=&v"(f2v), "=&v"(f3v) : "v"(fL1a), "v"(fL1b) : "memory");
            if (__all((f2v >= TT + 1) && (f3v >= TT + 1))) break;
            if (++bail > (1<<22)) break;
            __builtin_amdgcn_s_sleep(1);
        }
        __syncthreads();
        int col = TT - 8 + j, slot = col & 7;     // 1020..1023
        const float* o1 = op + ((slot * NC + c) * 32 + (tid & 15)) * 16 + (tid >> 4);
        float2 vv = ldf2_coh(o1, o1 + 256);
        float v = vv.x + vv.y;
        v += __shfl_down(v, 8, 16);
        v += __shfl_down(v, 4, 16);
        v += __shfl_down(v, 2, 16);
        v += __shfl_down(v, 1, 16);
        if ((tid & 15) == 0) out[(c * 16 + (tid >> 4)) * TT + col] = v + blin_r;
    }
}

extern "C" void kernel_launch(void* const* d_in, const int* in_sizes, int n_in,
                              void* d_out, int out_size, void* d_ws, size_t ws_size,
                              hipStream_t stream)
{
    const float* x    = (const float*)d_in[0];
    const float* Wih0 = (const float*)d_in[1];
    const float* Whh0 = (const float*)d_in[2];
    const float* bih0 = (const float*)d_in[3];
    const float* bhh0 = (const float*)d_in[4];
    const float* Wih1 = (const float*)d_in[5];
    const float* Whh1 = (const float*)d_in[6];
    const float* bih1 = (const float*)d_in[7];
    const float* bhh1 = (const float*)d_in[8];
    const float* Wlin = (const float*)d_in[9];
    const float* blin = (const float*)d_in[10];
    float* out = (float*)d_out;
    char* ws   = (char*)d_ws;

    // 256 blocks x 256 threads, 1 block/CU -> all co-resident (spin-safe).
    lstm_kernel<<<dim3(256), dim3(256), 0, stream>>>(
        x, Wih0, Whh0, bih0, bhh0, Wih1, Whh1, bih1, bhh1, Wlin, blin, out, ws);
}